// Round 6
// baseline (441.649 us; speedup 1.0000x reference)
//
#include <hip/hip_runtime.h>

// 2-layer LSTM (B=4096, T=256, I=38, H1=50, H2=15) + FC on last step.
// R6: SB=4 seqs/block, 4 waves, grid=1024 -> 4 independent blocks/CU
// (launch_bounds(256,4)). One barrier per step (wave-private pre-act
// round-trip). Conflict-free LDS strides: bufA 288B rows, pre 64B rows.
// Two-step-ahead x prefetch. L2 pipelined one step behind L1.

typedef _Float16 f16x8 __attribute__((ext_vector_type(8)));
typedef float    f32x4 __attribute__((ext_vector_type(4)));

#if __has_builtin(__builtin_amdgcn_exp2f)
#define DEV_EXP2(x) __builtin_amdgcn_exp2f(x)
#else
#define DEV_EXP2(x) exp2f(x)
#endif
#if __has_builtin(__builtin_amdgcn_rcpf)
#define DEV_RCP(x) __builtin_amdgcn_rcpf(x)
#else
#define DEV_RCP(x) (1.0f/(x))
#endif

#define I1 38
#define H1 50
#define H2 15
#define NC 14
#define TT 256
#define SB 4
// A-row (f16): [x:0..37 | h1:38..87 | h2:88..102 | zero:..127 | pad..143]
#define XS 144
#define NTH 256
#define NSLOT 5
#define NQ 65
#define PREW 320       // f32 per wave: 5 slots x 4 seqs x 16 cols
#define L2E 2.885390081777927f
#define L1E 1.442695040888963f

__device__ __forceinline__ float sigm(float v)  { return DEV_RCP(1.f + DEV_EXP2(-L1E * v)); }
__device__ __forceinline__ float tanh_f(float v){ return 1.f - 2.f * DEV_RCP(1.f + DEV_EXP2(L2E * v)); }

__launch_bounds__(NTH, 4)
__global__ void lstm2_fused(const float* __restrict__ x,
                            const float* __restrict__ w_ih1, const float* __restrict__ w_hh1,
                            const float* __restrict__ b_ih1, const float* __restrict__ b_hh1,
                            const float* __restrict__ w_ih2, const float* __restrict__ w_hh2,
                            const float* __restrict__ b_ih2, const float* __restrict__ b_hh2,
                            const float* __restrict__ w_fc, const float* __restrict__ b_fc,
                            float* __restrict__ out)
{
  __shared__ __align__(16) _Float16 bufA[2][SB][XS];
  __shared__ __align__(16) float    s_preb[4 * PREW];

  const int tid  = threadIdx.x;
  const int wv   = tid >> 6;
  const int lane = tid & 63;
  const int lm   = lane & 15;
  const int lk   = lane >> 4;
  const int arow = lm & 3;            // A-read row (seq), 4x duplicated -> broadcast
  const int blk  = blockIdx.x;
  const float* xblk = x + (size_t)blk * SB * TT * I1;

  // ---- zero A buffers ----
  for (int i = tid; i < 2*SB*XS; i += NTH) ((_Float16*)bufA)[i] = (_Float16)0.f;

  // ---- slots: wave wv owns tiles {wv, wv+4, wv+8, wv+12}; wv3 also tile 16 ----
  bool sval_[NSLOT], colv_[NSLOT];
  int  kmask_[NSLOT];
  float sb_[NSLOT];
  f16x8 W[NSLOT][4];
  #pragma unroll
  for (int s = 0; s < NSLOT; ++s) {
    const int  t = (s < 4) ? (wv + 4*s) : 16;
    const bool v = (s < 4) || (wv == 3);
    sval_[s] = v;
    kmask_[s] = (t < 12) ? 0x7 : (t == 12 ? 0xF : 0xE);
    const int r  = t*16 + lm;          // gate-row r' = 4u+g
    const int qi = r >> 2;
    const bool il1 = (qi < H1);
    const int  u   = il1 ? qi : (qi - H1);
    const int  g   = r & 3;
    colv_[s] = v && (qi < NQ);
    float b = 0.f;
    if (colv_[s])
      b = il1 ? (b_ih1[g*H1 + u] + b_hh1[g*H1 + u])
              : (b_ih2[g*H2 + u] + b_hh2[g*H2 + u]);
    sb_[s] = b;
    #pragma unroll
    for (int ks = 0; ks < 4; ++ks) {
      f16x8 vv;
      #pragma unroll
      for (int e = 0; e < 8; ++e) {
        const int k = ks*32 + lk*8 + e;
        float w = 0.f;
        if (colv_[s]) {
          if (il1) {
            if (k < I1)                w = w_ih1[(g*H1 + u)*I1 + k];
            else if (k < I1 + H1)      w = w_hh1[(g*H1 + u)*H1 + (k - I1)];
          } else {
            if (k >= I1 && k < I1+H1)             w = w_ih2[(g*H2 + u)*H1 + (k - I1)];
            else if (k >= I1+H1 && k < I1+H1+H2)  w = w_hh2[(g*H2 + u)*H2 + (k - I1 - H1)];
          }
        }
        vv[e] = (_Float16)w;
      }
      W[s][ks] = vv;
    }
  }

  // ---- x staging map: 152 f32/step, threads 0..151 ----
  const bool vx = (tid < SB*I1);
  const int s0 = vx ? (tid / I1) : 0, k0 = vx ? (tid % I1) : 0;
  const int gb0 = s0*TT*I1 + k0;
  const int lb0 = s0*XS + k0;

  // ---- update pair A: lane = sA*16 + seqA*4 + ulp  (64 = 4 slots x 4 seqs x 4 units) ----
  const int sA   = lane >> 4;          // slot 0..3
  const int seqA = (lane >> 2) & 3;
  const int ulp  = lane & 3;
  const int uA   = 4*(wv + 4*sA) + ulp;
  const bool il1A = (uA < H1);
  const int dA   = il1A ? (38 + uA) : (88 + uA - H1);
  const int preA = wv*PREW + sA*64 + seqA*16 + 4*ulp;
  // pair C: wv3 slot 4 (tile 16 -> unit 64 = L2 u14), lanes 0..3 = seqs
  const bool hasC = (wv == 3) && (lane < 4);
  const int seqC = lane & 3;
  const int preC = 3*PREW + 4*64 + seqC*16;
  const int dC   = 102;

  __syncthreads();              // zeros visible
  if (vx) bufA[0][s0][k0] = (_Float16)xblk[gb0];   // stage x(0)
  float xA0 = 0.f, xB0 = 0.f;
  if (vx) xA0 = xblk[gb0 + I1];                    // prefetch x(1)
  __syncthreads();

  float cA = 0.f, cC = 0.f;

#define STEP(T, XC0, XN0) do {                                                  \
    _Float16* cur = &bufA[(T) & 1][0][0];                                       \
    _Float16* nxt = &bufA[((T) & 1) ^ 1][0][0];                                 \
    if (vx && (T) + 2 < TT) XN0 = xblk[gb0 + ((T) + 2) * I1];                   \
    f16x8 a[4];                                                                 \
    _Pragma("unroll")                                                           \
    for (int ks = 0; ks < 4; ++ks)                                              \
      a[ks] = *(const f16x8*)(cur + arow*XS + ks*32 + lk*8);                    \
    _Pragma("unroll")                                                           \
    for (int s = 0; s < NSLOT; ++s) {                                           \
      if (!sval_[s]) continue;                                                  \
      f32x4 acc = (f32x4){sb_[s], sb_[s], sb_[s], sb_[s]};                      \
      const int km = kmask_[s];                                                 \
      _Pragma("unroll")                                                         \
      for (int ks = 0; ks < 4; ++ks)                                            \
        if (km & (1 << ks))                                                     \
          acc = __builtin_amdgcn_mfma_f32_16x16x32_f16(a[ks], W[s][ks], acc, 0, 0, 0); \
      if (lk == 0) {                                                            \
        _Pragma("unroll")                                                       \
        for (int m = 0; m < 4; ++m)                                             \
          s_preb[wv*PREW + s*64 + m*16 + lm] = acc[m];                          \
      }                                                                         \
    }                                                                           \
    { const bool up = il1A ? ((T) < TT) : ((T) >= 1);                           \
      if (up) { f32x4 p = *(const f32x4*)&s_preb[preA];                         \
        float ig = sigm(p[0]), fg = sigm(p[1]);                                 \
        float gg = tanh_f(p[2]), og = sigm(p[3]);                               \
        cA = fg*cA + ig*gg;                                                     \
        nxt[seqA*XS + dA] = (_Float16)(og * tanh_f(cA)); } }                    \
    if (hasC && (T) >= 1) {                                                     \
      f32x4 p = *(const f32x4*)&s_preb[preC];                                   \
      float ig = sigm(p[0]), fg = sigm(p[1]);                                   \
      float gg = tanh_f(p[2]), og = sigm(p[3]);                                 \
      cC = fg*cC + ig*gg;                                                       \
      nxt[seqC*XS + dC] = (_Float16)(og * tanh_f(cC)); }                        \
    if (vx && (T) + 1 < TT) nxt[lb0] = (_Float16)XC0;                           \
    __syncthreads();                                                            \
  } while (0)

  int t = 0;
  for (;;) {
    STEP(t, xA0, xB0);
    if (++t > TT) break;
    STEP(t, xB0, xA0);
    if (++t > TT) break;
  }
#undef STEP

  // ---- FC on h2(255) (bufA[1], cols 88..102) ----
  if (tid < SB*NC) {
    int s = tid / NC, n = tid % NC;
    float acc = b_fc[n];
    #pragma unroll
    for (int u = 0; u < H2; ++u)
      acc += (float)bufA[1][s][88 + u] * w_fc[n*H2 + u];
    out[((size_t)blk*SB + s)*NC + n] = acc;
  }
}

extern "C" void kernel_launch(void* const* d_in, const int* in_sizes, int n_in,
                              void* d_out, int out_size, void* d_ws, size_t ws_size,
                              hipStream_t stream) {
  (void)n_in; (void)d_ws; (void)ws_size; (void)out_size;
  const float* x     = (const float*)d_in[0];
  const float* w_ih1 = (const float*)d_in[1];
  const float* w_hh1 = (const float*)d_in[2];
  const float* b_ih1 = (const float*)d_in[3];
  const float* b_hh1 = (const float*)d_in[4];
  const float* w_ih2 = (const float*)d_in[5];
  const float* w_hh2 = (const float*)d_in[6];
  const float* b_ih2 = (const float*)d_in[7];
  const float* b_hh2 = (const float*)d_in[8];
  const float* w_fc  = (const float*)d_in[9];
  const float* b_fc  = (const float*)d_in[10];
  float* out = (float*)d_out;

  const int B = in_sizes[0] / (TT * I1);   // 4096
  dim3 grid(B / SB), block(NTH);
  lstm2_fused<<<grid, block, 0, stream>>>(x, w_ih1, w_hh1, b_ih1, b_hh1,
                                          w_ih2, w_hh2, b_ih2, b_hh2,
                                          w_fc, b_fc, out);
}

// Round 7
// 205.009 us; speedup vs baseline: 2.1543x; 2.1543x over previous
//
#include <hip/hip_runtime.h>

// 2-layer LSTM (B=4096, T=256, I=38, H1=50, H2=15) + FC on last step.
// R7: 512-thr blocks (8 waves), SB=8, grid=512 -> 2 blocks/CU = 4 waves/SIMD
// from 2 independent barrier domains. Weights spread over 8 waves (~2 tiles
// each, ~105 VGPR, no spill at launch_bounds(512,4)). One barrier per step;
// wave-private pre-act round-trip in transposed conflict-free LDS layout
// [tile][col][20]. Two-step-ahead x prefetch. L2 one step behind L1.

typedef _Float16 f16x8 __attribute__((ext_vector_type(8)));
typedef float    f32x4 __attribute__((ext_vector_type(4)));

#if __has_builtin(__builtin_amdgcn_exp2f)
#define DEV_EXP2(x) __builtin_amdgcn_exp2f(x)
#else
#define DEV_EXP2(x) exp2f(x)
#endif
#if __has_builtin(__builtin_amdgcn_rcpf)
#define DEV_RCP(x) __builtin_amdgcn_rcpf(x)
#else
#define DEV_RCP(x) (1.0f/(x))
#endif

#define I1 38
#define H1 50
#define H2 15
#define NC 14
#define TT 256
#define SB 8
// A-row (f16): [x:0..37 | h1:38..87 | h2:88..102 | zero:..127 | pad..135]
#define XS 136
#define NTH 512
#define PSTR 20        // pre-act seq-stride (f32): conflict-free r/w
#define L2E 2.885390081777927f
#define L1E 1.442695040888963f

__device__ __forceinline__ float sigm(float v)  { return DEV_RCP(1.f + DEV_EXP2(-L1E * v)); }
__device__ __forceinline__ float tanh_f(float v){ return 1.f - 2.f * DEV_RCP(1.f + DEV_EXP2(L2E * v)); }

__launch_bounds__(NTH, 4)
__global__ void lstm2_fused(const float* __restrict__ x,
                            const float* __restrict__ w_ih1, const float* __restrict__ w_hh1,
                            const float* __restrict__ b_ih1, const float* __restrict__ b_hh1,
                            const float* __restrict__ w_ih2, const float* __restrict__ w_hh2,
                            const float* __restrict__ b_ih2, const float* __restrict__ b_hh2,
                            const float* __restrict__ w_fc, const float* __restrict__ b_fc,
                            float* __restrict__ out)
{
  __shared__ __align__(16) _Float16 bufA[2][SB][XS];
  __shared__ __align__(16) float    s_pre[17][16][PSTR];   // [tile][col][seq+pad]

  const int tid  = threadIdx.x;
  const int wv   = tid >> 6;          // 0..7
  const int lane = tid & 63;
  const int lm   = lane & 15;
  const int lk   = lane >> 4;
  const int arow = lm & 7;            // A-read seq row (rows 8-15 duplicate 0-7)
  const int blk  = blockIdx.x;
  const float* xblk = x + (size_t)blk * SB * TT * I1;

  // ---- zero A buffers ----
  for (int i = tid; i < 2*SB*XS; i += NTH) ((_Float16*)bufA)[i] = (_Float16)0.f;

  // ---- weight element fetch (unified-k, gate-row r = 4u+g) ----
  auto welem = [&](bool il1, bool valid, int u, int g, int k) -> _Float16 {
    float w = 0.f;
    if (valid) {
      if (il1) {
        if (k < I1)                w = w_ih1[(g*H1 + u)*I1 + k];
        else if (k < I1 + H1)      w = w_hh1[(g*H1 + u)*H1 + (k - I1)];
      } else {
        if (k >= I1 && k < I1+H1)             w = w_ih2[(g*H2 + u)*H1 + (k - I1)];
        else if (k >= I1+H1 && k < I1+H1+H2)  w = w_hh2[(g*H2 + u)*H2 + (k - I1 - H1)];
      }
    }
    return (_Float16)w;
  };

  // ---- slot geometry: wave wv owns tiles {wv, wv+8}; wv0 also tile 16 ----
  const int t1 = wv + 8;
  const int km1 = (t1 < 12) ? 0x7 : (t1 == 12 ? 0xF : 0xE);
  // slot0: tile wv (quads < 32 -> always L1)
  const int r0 = wv*16 + lm, u0q = r0 >> 2, g0 = r0 & 3;
  // slot1: tile wv+8
  const int r1 = t1*16 + lm, q1 = r1 >> 2, g1 = r1 & 3;
  const bool il1s1 = (q1 < H1);
  const int  u1 = il1s1 ? q1 : (q1 - H1);
  // tile16 (wv0 only): cols lm<4 valid (quad 64 = L2 u14)
  const bool w16 = (wv == 0);
  const bool c16 = w16 && (lm < 4);

  float sb0, sb1, sb16;
  sb0 = b_ih1[g0*H1 + u0q] + b_hh1[g0*H1 + u0q];
  sb1 = il1s1 ? (b_ih1[g1*H1 + u1] + b_hh1[g1*H1 + u1])
              : (b_ih2[g1*H2 + u1] + b_hh2[g1*H2 + u1]);
  sb16 = c16 ? (b_ih2[lm*H2 + 14] + b_hh2[lm*H2 + 14]) : 0.f;   // g = lm for lm<4

  f16x8 W0[3], W1[4], W16[3];
  #pragma unroll
  for (int ks = 0; ks < 3; ++ks) {
    f16x8 v;
    #pragma unroll
    for (int e = 0; e < 8; ++e) v[e] = welem(true, true, u0q, g0, ks*32 + lk*8 + e);
    W0[ks] = v;
  }
  #pragma unroll
  for (int ks = 0; ks < 4; ++ks) {
    f16x8 v;
    #pragma unroll
    for (int e = 0; e < 8; ++e) v[e] = welem(il1s1, true, u1, g1, ks*32 + lk*8 + e);
    W1[ks] = v;
  }
  #pragma unroll
  for (int j = 0; j < 3; ++j) {
    f16x8 v;
    #pragma unroll
    for (int e = 0; e < 8; ++e) v[e] = welem(false, c16, 14, lm & 3, (j+1)*32 + lk*8 + e);
    W16[j] = v;
  }

  // ---- update mapping: 1 pair/lane; lane = sl*32 + sequ*4 + qlp ----
  const int sl   = lane >> 5;
  const int l5   = lane & 31;
  const int qlp  = l5 & 3;
  const int sequ = l5 >> 2;           // 0..7
  const int tileU = sl ? t1 : wv;
  const int quad  = 4*tileU + qlp;
  const bool il1U = (quad < H1);
  const int  uU   = il1U ? quad : (quad - H1);
  const int  dU   = il1U ? (38 + uU) : (88 + uU);
  const float* preU = &s_pre[tileU][4*qlp][sequ];
  // extra pair (wv0 lanes 0-7): tile16 quad 64 -> L2 u14
  const bool hasC = w16 && (lane < 8);
  const int  seqC = lane & 7;
  const float* preC = &s_pre[16][0][seqC];

  // ---- x staging: 304 f32/step, threads 0..303 ----
  const bool vx = (tid < SB*I1);
  const int s0 = vx ? (tid / I1) : 0, k0 = vx ? (tid % I1) : 0;
  const int gb0 = s0*TT*I1 + k0;
  const int lb0 = s0*XS + k0;

  __syncthreads();              // zeros visible
  if (vx) bufA[0][s0][k0] = (_Float16)xblk[gb0];   // stage x(0)
  float xA0 = 0.f, xB0 = 0.f;
  if (vx) xA0 = xblk[gb0 + I1];                    // prefetch x(1)
  __syncthreads();

  float cU = 0.f, cC = 0.f;

#define STEP(T, XC0, XN0) do {                                                  \
    _Float16* cur = &bufA[(T) & 1][0][0];                                       \
    _Float16* nxt = &bufA[((T) & 1) ^ 1][0][0];                                 \
    if (vx && (T) + 2 < TT) XN0 = xblk[gb0 + ((T) + 2) * I1];                   \
    f16x8 a[4];                                                                 \
    _Pragma("unroll")                                                           \
    for (int ks = 0; ks < 4; ++ks)                                              \
      a[ks] = *(const f16x8*)(cur + arow*XS + ks*32 + lk*8);                    \
    {                                                                           \
      f32x4 acc0 = (f32x4){sb0, sb0, sb0, sb0};                                 \
      _Pragma("unroll")                                                         \
      for (int ks = 0; ks < 3; ++ks)                                            \
        acc0 = __builtin_amdgcn_mfma_f32_16x16x32_f16(a[ks], W0[ks], acc0, 0, 0, 0); \
      if (lk < 2) *(f32x4*)&s_pre[wv][lm][4*lk] = acc0;                         \
    }                                                                           \
    {                                                                           \
      f32x4 acc1 = (f32x4){sb1, sb1, sb1, sb1};                                 \
      _Pragma("unroll")                                                         \
      for (int ks = 0; ks < 4; ++ks)                                            \
        if (km1 & (1 << ks))                                                    \
          acc1 = __builtin_amdgcn_mfma_f32_16x16x32_f16(a[ks], W1[ks], acc1, 0, 0, 0); \
      if (lk < 2) *(f32x4*)&s_pre[t1][lm][4*lk] = acc1;                         \
    }                                                                           \
    if (w16) {                                                                  \
      f32x4 acc2 = (f32x4){sb16, sb16, sb16, sb16};                             \
      _Pragma("unroll")                                                         \
      for (int j = 0; j < 3; ++j)                                               \
        acc2 = __builtin_amdgcn_mfma_f32_16x16x32_f16(a[j+1], W16[j], acc2, 0, 0, 0); \
      if (lk < 2) *(f32x4*)&s_pre[16][lm][4*lk] = acc2;                         \
    }                                                                           \
    { const bool up = il1U ? ((T) < TT) : ((T) >= 1);                           \
      if (up) {                                                                 \
        float p0 = preU[0], p1 = preU[PSTR], p2 = preU[2*PSTR], p3 = preU[3*PSTR]; \
        float ig = sigm(p0), fg = sigm(p1);                                     \
        float gg = tanh_f(p2), og = sigm(p3);                                   \
        cU = fg*cU + ig*gg;                                                     \
        nxt[sequ*XS + dU] = (_Float16)(og * tanh_f(cU));                        \
      } }                                                                       \
    if (hasC && (T) >= 1) {                                                     \
      float p0 = preC[0], p1 = preC[PSTR], p2 = preC[2*PSTR], p3 = preC[3*PSTR];\
      float ig = sigm(p0), fg = sigm(p1);                                       \
      float gg = tanh_f(p2), og = sigm(p3);                                     \
      cC = fg*cC + ig*gg;                                                       \
      nxt[seqC*XS + 102] = (_Float16)(og * tanh_f(cC));                         \
    }                                                                           \
    if (vx && (T) + 1 < TT) nxt[lb0] = (_Float16)XC0;                           \
    __syncthreads();                                                            \
  } while (0)

  int t = 0;
  for (;;) {
    STEP(t, xA0, xB0);
    if (++t > TT) break;
    STEP(t, xB0, xA0);
    if (++t > TT) break;
  }
#undef STEP

  // ---- FC on h2(255) (bufA[1], cols 88..102) ----
  if (tid < SB*NC) {
    int s = tid / NC, n = tid % NC;
    float acc = b_fc[n];
    #pragma unroll
    for (int u = 0; u < H2; ++u)
      acc += (float)bufA[1][s][88 + u] * w_fc[n*H2 + u];
    out[((size_t)blk*SB + s)*NC + n] = acc;
  }
}

extern "C" void kernel_launch(void* const* d_in, const int* in_sizes, int n_in,
                              void* d_out, int out_size, void* d_ws, size_t ws_size,
                              hipStream_t stream) {
  (void)n_in; (void)d_ws; (void)ws_size; (void)out_size;
  const float* x     = (const float*)d_in[0];
  const float* w_ih1 = (const float*)d_in[1];
  const float* w_hh1 = (const float*)d_in[2];
  const float* b_ih1 = (const float*)d_in[3];
  const float* b_hh1 = (const float*)d_in[4];
  const float* w_ih2 = (const float*)d_in[5];
  const float* w_hh2 = (const float*)d_in[6];
  const float* b_ih2 = (const float*)d_in[7];
  const float* b_hh2 = (const float*)d_in[8];
  const float* w_fc  = (const float*)d_in[9];
  const float* b_fc  = (const float*)d_in[10];
  float* out = (float*)d_out;

  const int B = in_sizes[0] / (TT * I1);   // 4096
  dim3 grid(B / SB), block(NTH);
  lstm2_fused<<<grid, block, 0, stream>>>(x, w_ih1, w_hh1, b_ih1, b_hh1,
                                          w_ih2, w_hh2, b_ih2, b_hh2,
                                          w_fc, b_fc, out);
}